// Round 1
// baseline (904.079 us; speedup 1.0000x reference)
//
#include <hip/hip_runtime.h>

#define N0c 1200000
#define N1c 120000
#define N2c 12000
#define E0c 1200000
#define E1c 120000

typedef short short8 __attribute__((ext_vector_type(8)));
typedef float f32x4 __attribute__((ext_vector_type(4)));
typedef unsigned short u16;

__device__ __forceinline__ u16 f2bf(float f) {
    union { float f; unsigned u; } v; v.f = f;
    unsigned r = v.u + 0x7FFFu + ((v.u >> 16) & 1u);
    return (u16)(r >> 16);
}
__device__ __forceinline__ float bf2f(u16 h) {
    union { unsigned u; float f; } v; v.u = ((unsigned)h) << 16;
    return v.f;
}

// ---------------- CSR build ----------------
__global__ void k_hist(const int* __restrict__ dst, int* __restrict__ cnt, int n) {
    int i = blockIdx.x * blockDim.x + threadIdx.x;
    if (i < n) atomicAdd(&cnt[dst[i]], 1);
}

__global__ void k_scan(const int* __restrict__ cnt, int* __restrict__ rs, int n) {
    __shared__ int part[1024];
    int tid = threadIdx.x;
    int chunk = (n + 1023) >> 10;
    int base = tid * chunk;
    int s = 0;
    for (int i = 0; i < chunk; ++i) { int j = base + i; if (j < n) s += cnt[j]; }
    part[tid] = s;
    __syncthreads();
    if (tid == 0) {
        int run = 0;
        for (int i = 0; i < 1024; ++i) { int t = part[i]; part[i] = run; run += t; }
        rs[n] = run;
    }
    __syncthreads();
    int run = part[tid];
    for (int i = 0; i < chunk; ++i) {
        int j = base + i;
        if (j < n) { rs[j] = run; run += cnt[j]; }
    }
}

__global__ void k_scatter(const int* __restrict__ src, const int* __restrict__ dst,
                          const int* __restrict__ rs, int* __restrict__ cur,
                          int* __restrict__ eidx, int n) {
    int i = blockIdx.x * blockDim.x + threadIdx.x;
    if (i < n) {
        int d = dst[i];
        int p = rs[d] + atomicAdd(&cur[d], 1);
        eidx[p] = src[i];
    }
}

// ---------------- weight concat/convert: Bt[c][k] = k<256 ? Wl[c][k] : Wr[c][k-256]
__global__ void k_wcat(u16* __restrict__ dstw, const float* __restrict__ Wl,
                       const float* __restrict__ Wr, int CH, int CHpad) {
    int i = blockIdx.x * blockDim.x + threadIdx.x;
    if (i >= CHpad * 512) return;
    int c = i >> 9, k = i & 511;
    float v = 0.f;
    if (c < CH) v = (k < 256) ? Wl[c * 256 + k] : Wr[c * 256 + (k - 256)];
    dstw[i] = f2bf(v);
}

// ---------------- mean aggregation: one wave per target, lane = float4 column slice
__global__ void k_agg_f32(const float* __restrict__ x, const int* __restrict__ eidx,
                          const int* __restrict__ rs, u16* __restrict__ agg, int ntgt) {
    int w = (int)((blockIdx.x * blockDim.x + threadIdx.x) >> 6);
    int lane = threadIdx.x & 63;
    if (w >= ntgt) return;
    int s = rs[w], e = rs[w + 1];
    float a0 = 0.f, a1 = 0.f, a2 = 0.f, a3 = 0.f;
    for (int i = s; i < e; ++i) {
        long idx = eidx[i];
        const float4* r = (const float4*)(x + idx * 256);
        float4 v = r[lane];
        a0 += v.x; a1 += v.y; a2 += v.z; a3 += v.w;
    }
    int c = e - s; if (c < 1) c = 1;
    float sc = 1.f / (float)c;
    ushort4 o;
    o.x = f2bf(a0 * sc); o.y = f2bf(a1 * sc); o.z = f2bf(a2 * sc); o.w = f2bf(a3 * sc);
    *(ushort4*)(agg + (long)w * 256 + lane * 4) = o;
}

__global__ void k_agg_bf16(const u16* __restrict__ hsrc, const int* __restrict__ eidx,
                           const int* __restrict__ rs, u16* __restrict__ agg, int ntgt) {
    int w = (int)((blockIdx.x * blockDim.x + threadIdx.x) >> 6);
    int lane = threadIdx.x & 63;
    if (w >= ntgt) return;
    int s = rs[w], e = rs[w + 1];
    float a0 = 0.f, a1 = 0.f, a2 = 0.f, a3 = 0.f;
    for (int i = s; i < e; ++i) {
        long idx = eidx[i];
        const ushort4* r = (const ushort4*)(hsrc + idx * 256);
        ushort4 v = r[lane];
        a0 += bf2f(v.x); a1 += bf2f(v.y); a2 += bf2f(v.z); a3 += bf2f(v.w);
    }
    int c = e - s; if (c < 1) c = 1;
    float sc = 1.f / (float)c;
    ushort4 o;
    o.x = f2bf(a0 * sc); o.y = f2bf(a1 * sc); o.z = f2bf(a2 * sc); o.w = f2bf(a3 * sc);
    *(ushort4*)(agg + (long)w * 256 + lane * 4) = o;
}

// ---------------- MFMA GEMM: C[m][c] = sum_k A[m][k]*Bt[c][k] (+bias, opt relu)
// A = [agg rows | self rows], K=512 split at 256. Both LDS tiles [rows][K] with
// 80B padded row stride (odd multiple of 16B -> conflict-free b128 phases).
#define BM 128
#define BN 128
#define BK 32
#define LDK 40

template <bool SELF_F32, bool RELU_BF16>
__global__ __launch_bounds__(256)
void k_gemm(const u16* __restrict__ Aagg, const void* __restrict__ Aself,
            const u16* __restrict__ Bt, const float* __restrict__ bias,
            void* __restrict__ outp, int M, int Ncols, int ldo) {
    __shared__ u16 As[BM * LDK];
    __shared__ u16 Bs[BN * LDK];
    const int tid = threadIdx.x;
    const int lane = tid & 63, wid = tid >> 6;
    const int wm = wid >> 1, wn = wid & 1;
    const long m0 = (long)blockIdx.x * BM;
    const int n0 = blockIdx.y * BN;
    const int sr = tid >> 1, sh = tid & 1;  // staging: row, 16-elem half

    f32x4 acc[4][4];
#pragma unroll
    for (int i = 0; i < 4; ++i)
#pragma unroll
        for (int j = 0; j < 4; ++j) acc[i][j] = (f32x4){0.f, 0.f, 0.f, 0.f};

    int4 ra[2]; float4 rf[4]; int4 rb[2];

    auto load_tile = [&](int ks) {
        int k0 = ks * BK;
        long arow = m0 + sr;
        if (k0 < 256) {
            const int4* p = (const int4*)(Aagg + arow * 256 + k0 + sh * 16);
            ra[0] = p[0]; ra[1] = p[1];
        } else if (SELF_F32) {
            const float4* p =
                (const float4*)((const float*)Aself + arow * 256 + (k0 - 256) + sh * 16);
            rf[0] = p[0]; rf[1] = p[1]; rf[2] = p[2]; rf[3] = p[3];
        } else {
            const int4* p =
                (const int4*)((const u16*)Aself + arow * 256 + (k0 - 256) + sh * 16);
            ra[0] = p[0]; ra[1] = p[1];
        }
        const int4* q = (const int4*)(Bt + (long)(n0 + sr) * 512 + k0 + sh * 16);
        rb[0] = q[0]; rb[1] = q[1];
    };

    auto write_tile = [&](int ks) {
        int k0 = ks * BK;
        u16* da = As + sr * LDK + sh * 16;
        if (SELF_F32 && k0 >= 256) {
            union { u16 h[16]; int4 q[2]; } uu;
#pragma unroll
            for (int v4 = 0; v4 < 4; ++v4) {
                uu.h[v4 * 4 + 0] = f2bf(rf[v4].x);
                uu.h[v4 * 4 + 1] = f2bf(rf[v4].y);
                uu.h[v4 * 4 + 2] = f2bf(rf[v4].z);
                uu.h[v4 * 4 + 3] = f2bf(rf[v4].w);
            }
            ((int4*)da)[0] = uu.q[0];
            ((int4*)da)[1] = uu.q[1];
        } else {
            ((int4*)da)[0] = ra[0];
            ((int4*)da)[1] = ra[1];
        }
        u16* db = Bs + sr * LDK + sh * 16;
        ((int4*)db)[0] = rb[0];
        ((int4*)db)[1] = rb[1];
    };

    load_tile(0);
    const int NK = 512 / BK;  // 16
    for (int ks = 0; ks < NK; ++ks) {
        __syncthreads();           // previous iteration's ds_reads done
        write_tile(ks);
        __syncthreads();           // tile visible
        if (ks + 1 < NK) load_tile(ks + 1);  // overlap next global load with MFMA
        short8 af[4], bv[4];
        const int rr = lane & 15, gg = lane >> 4;
#pragma unroll
        for (int f = 0; f < 4; ++f) {
            af[f] = *(const short8*)(As + (wm * 64 + f * 16 + rr) * LDK + gg * 8);
            bv[f] = *(const short8*)(Bs + (wn * 64 + f * 16 + rr) * LDK + gg * 8);
        }
#pragma unroll
        for (int i = 0; i < 4; ++i)
#pragma unroll
            for (int j = 0; j < 4; ++j)
                acc[i][j] =
                    __builtin_amdgcn_mfma_f32_16x16x32_bf16(af[i], bv[j], acc[i][j], 0, 0, 0);
    }

    // epilogue: D row = (lane>>4)*4 + q, col = lane&15 (m89-verified layout)
#pragma unroll
    for (int j = 0; j < 4; ++j) {
        int col = n0 + wn * 64 + j * 16 + (lane & 15);
        if (col >= Ncols) continue;
        float bvl = bias[col];
#pragma unroll
        for (int i = 0; i < 4; ++i) {
            long row = m0 + wm * 64 + i * 16 + (lane >> 4) * 4;
#pragma unroll
            for (int q = 0; q < 4; ++q) {
                long r = row + q;
                if (r < M) {
                    float v = acc[i][j][q] + bvl;
                    if (RELU_BF16) {
                        v = v > 0.f ? v : 0.f;
                        ((u16*)outp)[r * (long)ldo + col] = f2bf(v);
                    } else {
                        ((float*)outp)[r * (long)ldo + col] = v;
                    }
                }
            }
        }
    }
}

// ---------------- log_softmax: one wave per row of 64
__global__ void k_lsm(const float* __restrict__ lg, float* __restrict__ out, int nrows) {
    int w = (int)((blockIdx.x * blockDim.x + threadIdx.x) >> 6);
    int lane = threadIdx.x & 63;
    if (w >= nrows) return;
    float v = lg[(long)w * 64 + lane];
    float m = v;
    for (int d = 32; d > 0; d >>= 1) m = fmaxf(m, __shfl_xor(m, d, 64));
    float ex = __expf(v - m);
    float s = ex;
    for (int d = 32; d > 0; d >>= 1) s += __shfl_xor(s, d, 64);
    out[(long)w * 64 + lane] = v - m - __logf(s);
}

extern "C" void kernel_launch(void* const* d_in, const int* in_sizes, int n_in,
                              void* d_out, int out_size, void* d_ws, size_t ws_size,
                              hipStream_t stream) {
    const float* x   = (const float*)d_in[0];
    const int* src0  = (const int*)d_in[1];
    const int* dst0  = (const int*)d_in[2];
    const int* src1  = (const int*)d_in[3];
    const int* dst1  = (const int*)d_in[4];
    const float* Wl0 = (const float*)d_in[5];
    const float* b0  = (const float*)d_in[6];
    const float* Wr0 = (const float*)d_in[7];
    const float* Wl1 = (const float*)d_in[8];
    const float* b1  = (const float*)d_in[9];
    const float* Wr1 = (const float*)d_in[10];

    char* base = (char*)d_ws;
    size_t off = 0;
    auto alloc = [&](size_t bytes) -> void* {
        off = (off + 255) & ~(size_t)255;
        void* p = base + off;
        off += bytes;
        return p;
    };
    const int N1pad = 120064, N2pad = 12032;  // multiples of BM
    int* rs0      = (int*)alloc((size_t)(N1c + 1) * 4);
    int* cnt0     = (int*)alloc((size_t)N1c * 4);
    int* eidx0    = (int*)alloc((size_t)E0c * 4);
    int* rs1      = (int*)alloc((size_t)(N2c + 1) * 4);
    int* cnt1     = (int*)alloc((size_t)N2c * 4);
    int* eidx1    = (int*)alloc((size_t)E1c * 4);
    u16* agg0     = (u16*)alloc((size_t)N1pad * 256 * 2);
    u16* hbuf     = (u16*)alloc((size_t)N1pad * 256 * 2);
    u16* agg1     = (u16*)alloc((size_t)N2pad * 256 * 2);
    u16* Bt0      = (u16*)alloc((size_t)256 * 512 * 2);
    u16* Bt1      = (u16*)alloc((size_t)128 * 512 * 2);
    float* logits = (float*)alloc((size_t)N2pad * 64 * 4);

    // CSR for both hops
    hipMemsetAsync(cnt0, 0, (size_t)N1c * 4, stream);
    hipMemsetAsync(cnt1, 0, (size_t)N2c * 4, stream);
    k_hist<<<(E0c + 255) / 256, 256, 0, stream>>>(dst0, cnt0, E0c);
    k_hist<<<(E1c + 255) / 256, 256, 0, stream>>>(dst1, cnt1, E1c);
    k_scan<<<1, 1024, 0, stream>>>(cnt0, rs0, N1c);
    k_scan<<<1, 1024, 0, stream>>>(cnt1, rs1, N2c);
    hipMemsetAsync(cnt0, 0, (size_t)N1c * 4, stream);
    hipMemsetAsync(cnt1, 0, (size_t)N2c * 4, stream);
    k_scatter<<<(E0c + 255) / 256, 256, 0, stream>>>(src0, dst0, rs0, cnt0, eidx0, E0c);
    k_scatter<<<(E1c + 255) / 256, 256, 0, stream>>>(src1, dst1, rs1, cnt1, eidx1, E1c);

    // weights -> bf16 [Wl | Wr] row-major-in-K
    k_wcat<<<(256 * 512 + 255) / 256, 256, 0, stream>>>(Bt0, Wl0, Wr0, 256, 256);
    k_wcat<<<(128 * 512 + 255) / 256, 256, 0, stream>>>(Bt1, Wl1, Wr1, 64, 128);

    // layer 0
    k_agg_f32<<<(N1c + 3) / 4, 256, 0, stream>>>(x, eidx0, rs0, agg0, N1c);
    dim3 g0(N1pad / BM, 2);
    k_gemm<true, true><<<g0, 256, 0, stream>>>(agg0, x, Bt0, b0, hbuf, N1c, 256, 256);

    // layer 1 (self features = rows 0..N2 of hbuf, no copy)
    k_agg_bf16<<<(N2c + 3) / 4, 256, 0, stream>>>(hbuf, eidx1, rs1, agg1, N2c);
    dim3 g1(N2pad / BM, 1);
    k_gemm<false, false><<<g1, 256, 0, stream>>>(agg1, hbuf, Bt1, b1, logits, N2c, 64, 64);

    k_lsm<<<(N2c + 3) / 4, 256, 0, stream>>>(logits, (float*)d_out, N2c);
}

// Round 2
// 870.027 us; speedup vs baseline: 1.0391x; 1.0391x over previous
//
#include <hip/hip_runtime.h>

#define N0c 1200000
#define N1c 120000
#define N2c 12000
#define E0c 1200000
#define E1c 120000

typedef short short8 __attribute__((ext_vector_type(8)));
typedef float f32x4 __attribute__((ext_vector_type(4)));
typedef unsigned short u16;

__device__ __forceinline__ u16 f2bf(float f) {
    union { float f; unsigned u; } v; v.f = f;
    unsigned r = v.u + 0x7FFFu + ((v.u >> 16) & 1u);
    return (u16)(r >> 16);
}
__device__ __forceinline__ float bf2f(u16 h) {
    union { unsigned u; float f; } v; v.u = ((unsigned)h) << 16;
    return v.f;
}

// ---------------- CSR build (both hops in one kernel each) ----------------
__global__ void k_hist2(const int* __restrict__ dst0, const int* __restrict__ dst1,
                        int* __restrict__ cnt0, int* __restrict__ cnt1) {
    int i = blockIdx.x * blockDim.x + threadIdx.x;
    if (i < E0c) atomicAdd(&cnt0[dst0[i]], 1);
    else if (i < E0c + E1c) atomicAdd(&cnt1[dst1[i - E0c]], 1);
}

__global__ void k_scan2(const int* __restrict__ cnt0, int* __restrict__ rs0,
                        const int* __restrict__ cnt1, int* __restrict__ rs1) {
    const int* cnt = blockIdx.x == 0 ? cnt0 : cnt1;
    int* rs        = blockIdx.x == 0 ? rs0  : rs1;
    int n          = blockIdx.x == 0 ? N1c  : N2c;
    __shared__ int part[1024];
    int tid = threadIdx.x;
    int chunk = (n + 1023) >> 10;
    int base = tid * chunk;
    int s = 0;
    for (int i = 0; i < chunk; ++i) { int j = base + i; if (j < n) s += cnt[j]; }
    part[tid] = s;
    __syncthreads();
    if (tid == 0) {
        int run = 0;
        for (int i = 0; i < 1024; ++i) { int t = part[i]; part[i] = run; run += t; }
        rs[n] = run;
    }
    __syncthreads();
    int run = part[tid];
    for (int i = 0; i < chunk; ++i) {
        int j = base + i;
        if (j < n) { rs[j] = run; run += cnt[j]; }
    }
}

// scatter via atomicSub cursor: leaves cnt[] == 0 afterwards (self-restoring
// across graph replays; memset at start only matters for first call's poison)
__global__ void k_scat2(const int* __restrict__ src0, const int* __restrict__ dst0,
                        const int* __restrict__ src1, const int* __restrict__ dst1,
                        const int* __restrict__ rs0, int* __restrict__ cnt0,
                        const int* __restrict__ rs1, int* __restrict__ cnt1,
                        int* __restrict__ eidx0, int* __restrict__ eidx1) {
    int i = blockIdx.x * blockDim.x + threadIdx.x;
    if (i < E0c) {
        int d = dst0[i];
        int p = rs0[d] + (atomicSub(&cnt0[d], 1) - 1);
        eidx0[p] = src0[i];
    } else if (i < E0c + E1c) {
        int j = i - E0c;
        int d = dst1[j];
        int p = rs1[d] + (atomicSub(&cnt1[d], 1) - 1);
        eidx1[p] = src1[j];
    }
}

// ---------------- weights -> bf16 [Wl | Wr] rows, both layers in one kernel
__global__ void k_wcat2(u16* __restrict__ Bt0, const float* __restrict__ Wl0,
                        const float* __restrict__ Wr0, u16* __restrict__ Bt1,
                        const float* __restrict__ Wl1, const float* __restrict__ Wr1) {
    int i = blockIdx.x * blockDim.x + threadIdx.x;
    if (i < 256 * 512) {
        int c = i >> 9, k = i & 511;
        float v = (k < 256) ? Wl0[c * 256 + k] : Wr0[c * 256 + (k - 256)];
        Bt0[i] = f2bf(v);
    } else if (i < 256 * 512 + 128 * 512) {
        int j = i - 256 * 512;
        int c = j >> 9, k = j & 511;
        float v = 0.f;
        if (c < 64) v = (k < 256) ? Wl1[c * 256 + k] : Wr1[c * 256 + (k - 256)];
        Bt1[j] = f2bf(v);
    }
}

// ---------------- aggregation: one wave per target; writes full A row
// A[w] = [ mean-agg (256) | bf16(self row) (256) ], row stride 512
__global__ void k_agg0(const float* __restrict__ x, const int* __restrict__ eidx,
                       const int* __restrict__ rs, u16* __restrict__ A, int ntgt) {
    int w = (int)((blockIdx.x * blockDim.x + threadIdx.x) >> 6);
    int lane = threadIdx.x & 63;
    if (w >= ntgt) return;
    int s = rs[w], e = rs[w + 1];
    float a0 = 0.f, a1 = 0.f, a2 = 0.f, a3 = 0.f;
    int i = s;
    for (; i + 4 <= e; i += 4) {  // 4 independent row loads in flight
        long i0 = eidx[i], i1 = eidx[i + 1], i2 = eidx[i + 2], i3 = eidx[i + 3];
        float4 v0 = ((const float4*)(x + i0 * 256))[lane];
        float4 v1 = ((const float4*)(x + i1 * 256))[lane];
        float4 v2 = ((const float4*)(x + i2 * 256))[lane];
        float4 v3 = ((const float4*)(x + i3 * 256))[lane];
        a0 += (v0.x + v1.x) + (v2.x + v3.x);
        a1 += (v0.y + v1.y) + (v2.y + v3.y);
        a2 += (v0.z + v1.z) + (v2.z + v3.z);
        a3 += (v0.w + v1.w) + (v2.w + v3.w);
    }
    for (; i < e; ++i) {
        long idx = eidx[i];
        float4 v = ((const float4*)(x + idx * 256))[lane];
        a0 += v.x; a1 += v.y; a2 += v.z; a3 += v.w;
    }
    int c = e - s; if (c < 1) c = 1;
    float sc = 1.f / (float)c;
    ushort4 o;
    o.x = f2bf(a0 * sc); o.y = f2bf(a1 * sc); o.z = f2bf(a2 * sc); o.w = f2bf(a3 * sc);
    *(ushort4*)(A + (long)w * 512 + lane * 4) = o;
    // self half
    float4 sv = ((const float4*)(x + (long)w * 256))[lane];
    ushort4 so;
    so.x = f2bf(sv.x); so.y = f2bf(sv.y); so.z = f2bf(sv.z); so.w = f2bf(sv.w);
    *(ushort4*)(A + (long)w * 512 + 256 + lane * 4) = so;
}

__global__ void k_agg1(const u16* __restrict__ hsrc, const int* __restrict__ eidx,
                       const int* __restrict__ rs, u16* __restrict__ A, int ntgt) {
    int w = (int)((blockIdx.x * blockDim.x + threadIdx.x) >> 6);
    int lane = threadIdx.x & 63;
    if (w >= ntgt) return;
    int s = rs[w], e = rs[w + 1];
    float a0 = 0.f, a1 = 0.f, a2 = 0.f, a3 = 0.f;
    int i = s;
    for (; i + 4 <= e; i += 4) {
        long i0 = eidx[i], i1 = eidx[i + 1], i2 = eidx[i + 2], i3 = eidx[i + 3];
        ushort4 v0 = ((const ushort4*)(hsrc + i0 * 256))[lane];
        ushort4 v1 = ((const ushort4*)(hsrc + i1 * 256))[lane];
        ushort4 v2 = ((const ushort4*)(hsrc + i2 * 256))[lane];
        ushort4 v3 = ((const ushort4*)(hsrc + i3 * 256))[lane];
        a0 += (bf2f(v0.x) + bf2f(v1.x)) + (bf2f(v2.x) + bf2f(v3.x));
        a1 += (bf2f(v0.y) + bf2f(v1.y)) + (bf2f(v2.y) + bf2f(v3.y));
        a2 += (bf2f(v0.z) + bf2f(v1.z)) + (bf2f(v2.z) + bf2f(v3.z));
        a3 += (bf2f(v0.w) + bf2f(v1.w)) + (bf2f(v2.w) + bf2f(v3.w));
    }
    for (; i < e; ++i) {
        long idx = eidx[i];
        ushort4 v = ((const ushort4*)(hsrc + idx * 256))[lane];
        a0 += bf2f(v.x); a1 += bf2f(v.y); a2 += bf2f(v.z); a3 += bf2f(v.w);
    }
    int c = e - s; if (c < 1) c = 1;
    float sc = 1.f / (float)c;
    ushort4 o;
    o.x = f2bf(a0 * sc); o.y = f2bf(a1 * sc); o.z = f2bf(a2 * sc); o.w = f2bf(a3 * sc);
    *(ushort4*)(A + (long)w * 512 + lane * 4) = o;
    // self half = hsrc row w (already bf16)
    ushort4 sv = ((const ushort4*)(hsrc + (long)w * 256))[lane];
    *(ushort4*)(A + (long)w * 512 + 256 + lane * 4) = sv;
}

// ---------------- MFMA GEMM: C[m][c] = sum_k A[m][k]*Bt[c][k] (+bias, opt relu)
// A pure bf16 [M][512]; Bt bf16 [BN-grid rows][512]. LDS rows padded to 80 B
// (odd multiple of 16 B -> 2-way-max bank aliasing on b128, free per m136).
#define BM 128
#define BN 128
#define BK 32
#define LDK 40

template <bool RELU_BF16>
__global__ __launch_bounds__(256)
void k_gemm(const u16* __restrict__ A, const u16* __restrict__ Bt,
            const float* __restrict__ bias, void* __restrict__ outp,
            int M, int Ncols, int ldo) {
    __shared__ u16 As[BM * LDK];
    __shared__ u16 Bs[BN * LDK];
    const int tid = threadIdx.x;
    const int lane = tid & 63, wid = tid >> 6;
    const int wm = wid >> 1, wn = wid & 1;
    const long m0 = (long)blockIdx.x * BM;
    const int n0 = blockIdx.y * BN;
    const int sr = tid >> 1, sh = tid & 1;  // staging: row, 16-elem half

    f32x4 acc[4][4];
#pragma unroll
    for (int i = 0; i < 4; ++i)
#pragma unroll
        for (int j = 0; j < 4; ++j) acc[i][j] = (f32x4){0.f, 0.f, 0.f, 0.f};

    int4 ra[2]; int4 rb[2];

    auto load_tile = [&](int ks) {
        int k0 = ks * BK;
        const int4* p = (const int4*)(A + (m0 + sr) * 512 + k0 + sh * 16);
        ra[0] = p[0]; ra[1] = p[1];
        const int4* q = (const int4*)(Bt + (long)(n0 + sr) * 512 + k0 + sh * 16);
        rb[0] = q[0]; rb[1] = q[1];
    };

    auto write_tile = [&]() {
        u16* da = As + sr * LDK + sh * 16;
        ((int4*)da)[0] = ra[0];
        ((int4*)da)[1] = ra[1];
        u16* db = Bs + sr * LDK + sh * 16;
        ((int4*)db)[0] = rb[0];
        ((int4*)db)[1] = rb[1];
    };

    load_tile(0);
    const int NK = 512 / BK;  // 16
    for (int ks = 0; ks < NK; ++ks) {
        __syncthreads();           // previous iteration's ds_reads done
        write_tile();
        __syncthreads();           // tile visible
        if (ks + 1 < NK) load_tile(ks + 1);  // overlap next global load with MFMA
        short8 af[4], bv[4];
        const int rr = lane & 15, gg = lane >> 4;
#pragma unroll
        for (int f = 0; f < 4; ++f) {
            af[f] = *(const short8*)(As + (wm * 64 + f * 16 + rr) * LDK + gg * 8);
            bv[f] = *(const short8*)(Bs + (wn * 64 + f * 16 + rr) * LDK + gg * 8);
        }
#pragma unroll
        for (int i = 0; i < 4; ++i)
#pragma unroll
            for (int j = 0; j < 4; ++j)
                acc[i][j] =
                    __builtin_amdgcn_mfma_f32_16x16x32_bf16(af[i], bv[j], acc[i][j], 0, 0, 0);
    }

    // epilogue: D row = (lane>>4)*4 + q, col = lane&15 (m89-verified layout)
#pragma unroll
    for (int j = 0; j < 4; ++j) {
        int col = n0 + wn * 64 + j * 16 + (lane & 15);
        if (col >= Ncols) continue;
        float bvl = bias[col];
#pragma unroll
        for (int i = 0; i < 4; ++i) {
            long row = m0 + wm * 64 + i * 16 + (lane >> 4) * 4;
#pragma unroll
            for (int q = 0; q < 4; ++q) {
                long r = row + q;
                if (r < M) {
                    float v = acc[i][j][q] + bvl;
                    if (RELU_BF16) {
                        v = v > 0.f ? v : 0.f;
                        ((u16*)outp)[r * (long)ldo + col] = f2bf(v);
                    } else {
                        ((float*)outp)[r * (long)ldo + col] = v;
                    }
                }
            }
        }
    }
}

// ---------------- log_softmax: one wave per row of 64
__global__ void k_lsm(const float* __restrict__ lg, float* __restrict__ out, int nrows) {
    int w = (int)((blockIdx.x * blockDim.x + threadIdx.x) >> 6);
    int lane = threadIdx.x & 63;
    if (w >= nrows) return;
    float v = lg[(long)w * 64 + lane];
    float m = v;
    for (int d = 32; d > 0; d >>= 1) m = fmaxf(m, __shfl_xor(m, d, 64));
    float ex = __expf(v - m);
    float s = ex;
    for (int d = 32; d > 0; d >>= 1) s += __shfl_xor(s, d, 64);
    out[(long)w * 64 + lane] = v - m - __logf(s);
}

extern "C" void kernel_launch(void* const* d_in, const int* in_sizes, int n_in,
                              void* d_out, int out_size, void* d_ws, size_t ws_size,
                              hipStream_t stream) {
    const float* x   = (const float*)d_in[0];
    const int* src0  = (const int*)d_in[1];
    const int* dst0  = (const int*)d_in[2];
    const int* src1  = (const int*)d_in[3];
    const int* dst1  = (const int*)d_in[4];
    const float* Wl0 = (const float*)d_in[5];
    const float* b0  = (const float*)d_in[6];
    const float* Wr0 = (const float*)d_in[7];
    const float* Wl1 = (const float*)d_in[8];
    const float* b1  = (const float*)d_in[9];
    const float* Wr1 = (const float*)d_in[10];

    char* base = (char*)d_ws;
    size_t off = 0;
    auto alloc = [&](size_t bytes) -> void* {
        off = (off + 255) & ~(size_t)255;
        void* p = base + off;
        off += bytes;
        return p;
    };
    const int N1pad = 120064, N2pad = 12032;  // multiples of BM
    int* rs0      = (int*)alloc((size_t)(N1c + 1) * 4);
    int* cnt0     = (int*)alloc((size_t)N1c * 4);
    int* eidx0    = (int*)alloc((size_t)E0c * 4);
    int* rs1      = (int*)alloc((size_t)(N2c + 1) * 4);
    int* cnt1     = (int*)alloc((size_t)N2c * 4);
    int* eidx1    = (int*)alloc((size_t)E1c * 4);
    u16* A0       = (u16*)alloc((size_t)N1pad * 512 * 2);  // [agg | self] bf16
    u16* hbuf     = (u16*)alloc((size_t)N1pad * 256 * 2);
    u16* A1       = (u16*)alloc((size_t)N2pad * 512 * 2);
    u16* Bt0      = (u16*)alloc((size_t)256 * 512 * 2);
    u16* Bt1      = (u16*)alloc((size_t)128 * 512 * 2);
    float* logits = (float*)alloc((size_t)N2pad * 64 * 4);

    // CSR for both hops (scatter restores cnt to 0 for replay determinism)
    hipMemsetAsync(cnt0, 0, (size_t)N1c * 4, stream);
    hipMemsetAsync(cnt1, 0, (size_t)N2c * 4, stream);
    const int Etot = E0c + E1c;
    k_hist2<<<(Etot + 255) / 256, 256, 0, stream>>>(dst0, dst1, cnt0, cnt1);
    k_scan2<<<2, 1024, 0, stream>>>(cnt0, rs0, cnt1, rs1);
    k_scat2<<<(Etot + 255) / 256, 256, 0, stream>>>(src0, dst0, src1, dst1,
                                                    rs0, cnt0, rs1, cnt1, eidx0, eidx1);

    // weights -> bf16 [Wl | Wr] row-major-in-K
    k_wcat2<<<(256 * 512 + 128 * 512 + 255) / 256, 256, 0, stream>>>(Bt0, Wl0, Wr0,
                                                                     Bt1, Wl1, Wr1);

    // layer 0
    k_agg0<<<(N1c + 3) / 4, 256, 0, stream>>>(x, eidx0, rs0, A0, N1c);
    dim3 g0(N1pad / BM, 2);
    k_gemm<true><<<g0, 256, 0, stream>>>(A0, Bt0, b0, hbuf, N1c, 256, 256);

    // layer 1
    k_agg1<<<(N2c + 3) / 4, 256, 0, stream>>>(hbuf, eidx1, rs1, A1, N2c);
    dim3 g1(N2pad / BM, 1);
    k_gemm<false><<<g1, 256, 0, stream>>>(A1, Bt1, b1, logits, N2c, 64, 64);

    k_lsm<<<(N2c + 3) / 4, 256, 0, stream>>>(logits, (float*)d_out, N2c);
}

// Round 3
// 592.005 us; speedup vs baseline: 1.5271x; 1.4696x over previous
//
#include <hip/hip_runtime.h>

#define N0c 1200000
#define N1c 120000
#define N2c 12000
#define E0c 1200000
#define E1c 120000
#define NB0 118   // ceil(N1c/1024)
#define NB1 12    // ceil(N2c/1024)

typedef short short8 __attribute__((ext_vector_type(8)));
typedef float f32x4 __attribute__((ext_vector_type(4)));
typedef unsigned short u16;

__device__ __forceinline__ u16 f2bf(float f) {
    union { float f; unsigned u; } v; v.f = f;
    unsigned r = v.u + 0x7FFFu + ((v.u >> 16) & 1u);
    return (u16)(r >> 16);
}
__device__ __forceinline__ float bf2f(u16 h) {
    union { unsigned u; float f; } v; v.u = ((unsigned)h) << 16;
    return v.f;
}

// ---------------- CSR build, XCD-partitioned (8 private count copies) -------
// hist and scat use the SAME grid and the SAME part=blockIdx&7 mapping, so
// every increment is matched by a decrement: c returns to 0 for the next
// replay (deterministic). part==XCD under round-robin dispatch (perf only).
__global__ void k_hist(const int* __restrict__ dst0, const int* __restrict__ dst1,
                       int* __restrict__ c0, int* __restrict__ c1) {
    int i = blockIdx.x * 256 + threadIdx.x;
    int part = blockIdx.x & 7;
    if (i < E0c) atomicAdd(&c0[part * N1c + dst0[i]], 1);
    else if (i < E0c + E1c) atomicAdd(&c1[part * N2c + dst1[i - E0c]], 1);
}

// per-block totals of sum over 8 copies
__global__ void k_scanA(const int* __restrict__ c0, const int* __restrict__ c1,
                        int* __restrict__ partials) {
    __shared__ int sh[256];
    int hop = blockIdx.x >= NB0;
    int blk = hop ? blockIdx.x - NB0 : blockIdx.x;
    const int* c = hop ? c1 : c0;
    int n = hop ? N2c : N1c;
    int d0 = blk * 1024 + threadIdx.x * 4;
    int tsum = 0;
#pragma unroll
    for (int j = 0; j < 4; ++j) {
        int d = d0 + j;
        if (d < n)
#pragma unroll
            for (int k = 0; k < 8; ++k) tsum += c[k * n + d];
    }
    sh[threadIdx.x] = tsum;
    __syncthreads();
    for (int ofs = 128; ofs > 0; ofs >>= 1) {
        if (threadIdx.x < ofs) sh[threadIdx.x] += sh[threadIdx.x + ofs];
        __syncthreads();
    }
    if (threadIdx.x == 0) partials[blockIdx.x] = sh[0];
}

// single-block exclusive scan of partials (both hop segments)
__global__ void k_scanB(int* __restrict__ partials, int* __restrict__ rs0,
                        int* __restrict__ rs1) {
    __shared__ int sh[256];
    int tid = threadIdx.x;
    int v0 = tid < NB0 ? partials[tid] : 0;
    sh[tid] = v0; __syncthreads();
    for (int ofs = 1; ofs < 256; ofs <<= 1) {
        int t = tid >= ofs ? sh[tid - ofs] : 0;
        __syncthreads();
        sh[tid] += t;
        __syncthreads();
    }
    if (tid < NB0) partials[tid] = sh[tid] - v0;
    __syncthreads();
    int v1 = tid < NB1 ? partials[NB0 + tid] : 0;
    sh[tid] = v1; __syncthreads();
    for (int ofs = 1; ofs < 256; ofs <<= 1) {
        int t = tid >= ofs ? sh[tid - ofs] : 0;
        __syncthreads();
        sh[tid] += t;
        __syncthreads();
    }
    if (tid < NB1) partials[NB0 + tid] = sh[tid] - v1;
    if (tid == 0) { rs0[N1c] = E0c; rs1[N2c] = E1c; }
}

// rebuild: rs[d] and per-copy segment bases bs[k][d]
__global__ void k_scanC(const int* __restrict__ c0, const int* __restrict__ c1,
                        const int* __restrict__ partials, int* __restrict__ rs0,
                        int* __restrict__ rs1, int* __restrict__ bs0,
                        int* __restrict__ bs1) {
    __shared__ int sh[256];
    int hop = blockIdx.x >= NB0;
    int blk = hop ? blockIdx.x - NB0 : blockIdx.x;
    const int* c = hop ? c1 : c0;
    int* rs = hop ? rs1 : rs0;
    int* bs = hop ? bs1 : bs0;
    int n = hop ? N2c : N1c;
    int tid = threadIdx.x;
    int d0 = blk * 1024 + tid * 4;
    int cv[4][8];
    int tsum = 0;
#pragma unroll
    for (int j = 0; j < 4; ++j)
#pragma unroll
        for (int k = 0; k < 8; ++k) {
            int d = d0 + j;
            int v = (d < n) ? c[k * n + d] : 0;
            cv[j][k] = v; tsum += v;
        }
    sh[tid] = tsum; __syncthreads();
    for (int ofs = 1; ofs < 256; ofs <<= 1) {
        int t = tid >= ofs ? sh[tid - ofs] : 0;
        __syncthreads();
        sh[tid] += t;
        __syncthreads();
    }
    int run = partials[blockIdx.x] + sh[tid] - tsum;  // block base + thread excl prefix
#pragma unroll
    for (int j = 0; j < 4; ++j) {
        int d = d0 + j;
        if (d < n) {
            rs[d] = run;
#pragma unroll
            for (int k = 0; k < 8; ++k) { bs[k * n + d] = run; run += cv[j][k]; }
        }
    }
}

__global__ void k_scat(const int* __restrict__ src0, const int* __restrict__ dst0,
                       const int* __restrict__ src1, const int* __restrict__ dst1,
                       int* __restrict__ c0, int* __restrict__ c1,
                       const int* __restrict__ bs0, const int* __restrict__ bs1,
                       int* __restrict__ eidx0, int* __restrict__ eidx1) {
    int i = blockIdx.x * 256 + threadIdx.x;
    int part = blockIdx.x & 7;
    if (i < E0c) {
        int d = dst0[i];
        int off = atomicSub(&c0[part * N1c + d], 1) - 1;
        eidx0[bs0[part * N1c + d] + off] = src0[i];
    } else if (i < E0c + E1c) {
        int j = i - E0c;
        int d = dst1[j];
        int off = atomicSub(&c1[part * N2c + d], 1) - 1;
        eidx1[bs1[part * N2c + d] + off] = src1[j];
    }
}

// ---------------- weights -> bf16 [Wl | Wr] rows, both layers ----------------
__global__ void k_wcat2(u16* __restrict__ Bt0, const float* __restrict__ Wl0,
                        const float* __restrict__ Wr0, u16* __restrict__ Bt1,
                        const float* __restrict__ Wl1, const float* __restrict__ Wr1) {
    int i = blockIdx.x * blockDim.x + threadIdx.x;
    if (i < 256 * 512) {
        int c = i >> 9, k = i & 511;
        float v = (k < 256) ? Wl0[c * 256 + k] : Wr0[c * 256 + (k - 256)];
        Bt0[i] = f2bf(v);
    } else if (i < 256 * 512 + 128 * 512) {
        int j = i - 256 * 512;
        int c = j >> 9, k = j & 511;
        float v = 0.f;
        if (c < 64) v = (k < 256) ? Wl1[c * 256 + k] : Wr1[c * 256 + (k - 256)];
        Bt1[j] = f2bf(v);
    }
}

// ---------------- aggregation: one wave per target; A[w]=[mean-agg|self] -----
__global__ void k_agg0(const float* __restrict__ x, const int* __restrict__ eidx,
                       const int* __restrict__ rs, u16* __restrict__ A, int ntgt) {
    int w = (int)((blockIdx.x * blockDim.x + threadIdx.x) >> 6);
    int lane = threadIdx.x & 63;
    if (w >= ntgt) return;
    int s = rs[w], e = rs[w + 1];
    float a0 = 0.f, a1 = 0.f, a2 = 0.f, a3 = 0.f;
    int i = s;
    for (; i + 8 <= e; i += 8) {  // 8 independent 1KB row loads in flight
        float4 v[8];
#pragma unroll
        for (int u = 0; u < 8; ++u) {
            long idx = eidx[i + u];
            v[u] = ((const float4*)(x + idx * 256))[lane];
        }
#pragma unroll
        for (int u = 0; u < 8; ++u) {
            a0 += v[u].x; a1 += v[u].y; a2 += v[u].z; a3 += v[u].w;
        }
    }
    for (; i + 2 <= e; i += 2) {
        long i0 = eidx[i], i1 = eidx[i + 1];
        float4 v0 = ((const float4*)(x + i0 * 256))[lane];
        float4 v1 = ((const float4*)(x + i1 * 256))[lane];
        a0 += v0.x + v1.x; a1 += v0.y + v1.y; a2 += v0.z + v1.z; a3 += v0.w + v1.w;
    }
    if (i < e) {
        long idx = eidx[i];
        float4 v = ((const float4*)(x + idx * 256))[lane];
        a0 += v.x; a1 += v.y; a2 += v.z; a3 += v.w;
    }
    int c = e - s; if (c < 1) c = 1;
    float sc = 1.f / (float)c;
    ushort4 o;
    o.x = f2bf(a0 * sc); o.y = f2bf(a1 * sc); o.z = f2bf(a2 * sc); o.w = f2bf(a3 * sc);
    *(ushort4*)(A + (long)w * 512 + lane * 4) = o;
    float4 sv = ((const float4*)(x + (long)w * 256))[lane];
    ushort4 so;
    so.x = f2bf(sv.x); so.y = f2bf(sv.y); so.z = f2bf(sv.z); so.w = f2bf(sv.w);
    *(ushort4*)(A + (long)w * 512 + 256 + lane * 4) = so;
}

__global__ void k_agg1(const u16* __restrict__ hsrc, const int* __restrict__ eidx,
                       const int* __restrict__ rs, u16* __restrict__ A, int ntgt) {
    int w = (int)((blockIdx.x * blockDim.x + threadIdx.x) >> 6);
    int lane = threadIdx.x & 63;
    if (w >= ntgt) return;
    int s = rs[w], e = rs[w + 1];
    float a0 = 0.f, a1 = 0.f, a2 = 0.f, a3 = 0.f;
    int i = s;
    for (; i + 4 <= e; i += 4) {
        long i0 = eidx[i], i1 = eidx[i + 1], i2 = eidx[i + 2], i3 = eidx[i + 3];
        ushort4 v0 = ((const ushort4*)(hsrc + i0 * 256))[lane];
        ushort4 v1 = ((const ushort4*)(hsrc + i1 * 256))[lane];
        ushort4 v2 = ((const ushort4*)(hsrc + i2 * 256))[lane];
        ushort4 v3 = ((const ushort4*)(hsrc + i3 * 256))[lane];
        a0 += (bf2f(v0.x) + bf2f(v1.x)) + (bf2f(v2.x) + bf2f(v3.x));
        a1 += (bf2f(v0.y) + bf2f(v1.y)) + (bf2f(v2.y) + bf2f(v3.y));
        a2 += (bf2f(v0.z) + bf2f(v1.z)) + (bf2f(v2.z) + bf2f(v3.z));
        a3 += (bf2f(v0.w) + bf2f(v1.w)) + (bf2f(v2.w) + bf2f(v3.w));
    }
    for (; i < e; ++i) {
        long idx = eidx[i];
        ushort4 v = ((const ushort4*)(hsrc + idx * 256))[lane];
        a0 += bf2f(v.x); a1 += bf2f(v.y); a2 += bf2f(v.z); a3 += bf2f(v.w);
    }
    int c = e - s; if (c < 1) c = 1;
    float sc = 1.f / (float)c;
    ushort4 o;
    o.x = f2bf(a0 * sc); o.y = f2bf(a1 * sc); o.z = f2bf(a2 * sc); o.w = f2bf(a3 * sc);
    *(ushort4*)(A + (long)w * 512 + lane * 4) = o;
    ushort4 sv = ((const ushort4*)(hsrc + (long)w * 256))[lane];
    *(ushort4*)(A + (long)w * 512 + 256 + lane * 4) = sv;
}

// ---------------- MFMA GEMM: C[m][c] = sum_k A[m][k]*Bt[c][k] (+bias, opt relu)
// BM=128 fixed, BN=WN*64, threads=128*WN (2*WN waves, 64x64 out each).
#define BM 128
#define BK 32
#define LDK 40

template <int WN, bool RELU_BF16>
__global__ __launch_bounds__(128 * WN)
void k_gemm(const u16* __restrict__ A, const u16* __restrict__ Bt,
            const float* __restrict__ bias, void* __restrict__ outp,
            int M, int Ncols, int ldo) {
    constexpr int BN_ = WN * 64;
    constexpr int APT = 4 / WN;  // int4 per thread staging A (WN=2 -> 2, WN=4 -> 1)
    constexpr int WSH = (WN == 4) ? 2 : 1;
    __shared__ u16 As[BM * LDK];
    __shared__ u16 Bs[BN_ * LDK];
    const int tid = threadIdx.x;
    const int lane = tid & 63, wid = tid >> 6;
    const int wm = wid >> WSH, wn = wid & (WN - 1);
    const long m0 = (long)blockIdx.x * BM;
    const int n0 = blockIdx.y * BN_;
    const int sar = tid / WN, sac = (tid % WN) * (APT * 8);  // u16 units
    const int sbr = tid >> 1, sbc = (tid & 1) * 16;

    f32x4 acc[4][4];
#pragma unroll
    for (int i = 0; i < 4; ++i)
#pragma unroll
        for (int j = 0; j < 4; ++j) acc[i][j] = (f32x4){0.f, 0.f, 0.f, 0.f};

    int4 ra[APT]; int4 rb[2];

    auto load_tile = [&](int ks) {
        int k0 = ks * BK;
        const int4* p = (const int4*)(A + (m0 + sar) * 512 + k0 + sac);
#pragma unroll
        for (int t = 0; t < APT; ++t) ra[t] = p[t];
        const int4* q = (const int4*)(Bt + (long)(n0 + sbr) * 512 + k0 + sbc);
        rb[0] = q[0]; rb[1] = q[1];
    };

    auto write_tile = [&]() {
        int4* da = (int4*)(As + sar * LDK + sac);
#pragma unroll
        for (int t = 0; t < APT; ++t) da[t] = ra[t];
        int4* db = (int4*)(Bs + sbr * LDK + sbc);
        db[0] = rb[0]; db[1] = rb[1];
    };

    load_tile(0);
    const int NK = 512 / BK;  // 16
    for (int ks = 0; ks < NK; ++ks) {
        __syncthreads();
        write_tile();
        __syncthreads();
        if (ks + 1 < NK) load_tile(ks + 1);
        short8 af[4], bv[4];
        const int rr = lane & 15, gg = lane >> 4;
#pragma unroll
        for (int f = 0; f < 4; ++f) {
            af[f] = *(const short8*)(As + (wm * 64 + f * 16 + rr) * LDK + gg * 8);
            bv[f] = *(const short8*)(Bs + (wn * 64 + f * 16 + rr) * LDK + gg * 8);
        }
#pragma unroll
        for (int i = 0; i < 4; ++i)
#pragma unroll
            for (int j = 0; j < 4; ++j)
                acc[i][j] =
                    __builtin_amdgcn_mfma_f32_16x16x32_bf16(af[i], bv[j], acc[i][j], 0, 0, 0);
    }

    // epilogue: D row = (lane>>4)*4 + q, col = lane&15 (m89-verified layout)
#pragma unroll
    for (int j = 0; j < 4; ++j) {
        int col = n0 + wn * 64 + j * 16 + (lane & 15);
        if (col >= Ncols) continue;
        float bvl = bias[col];
#pragma unroll
        for (int i = 0; i < 4; ++i) {
            long row = m0 + wm * 64 + i * 16 + (lane >> 4) * 4;
#pragma unroll
            for (int q = 0; q < 4; ++q) {
                long r = row + q;
                if (r < M) {
                    float v = acc[i][j][q] + bvl;
                    if (RELU_BF16) {
                        v = v > 0.f ? v : 0.f;
                        ((u16*)outp)[r * (long)ldo + col] = f2bf(v);
                    } else {
                        ((float*)outp)[r * (long)ldo + col] = v;
                    }
                }
            }
        }
    }
}

// ---------------- log_softmax: one wave per row of 64 ----------------
__global__ void k_lsm(const float* __restrict__ lg, float* __restrict__ out, int nrows) {
    int w = (int)((blockIdx.x * blockDim.x + threadIdx.x) >> 6);
    int lane = threadIdx.x & 63;
    if (w >= nrows) return;
    float v = lg[(long)w * 64 + lane];
    float m = v;
    for (int d = 32; d > 0; d >>= 1) m = fmaxf(m, __shfl_xor(m, d, 64));
    float ex = __expf(v - m);
    float s = ex;
    for (int d = 32; d > 0; d >>= 1) s += __shfl_xor(s, d, 64);
    out[(long)w * 64 + lane] = v - m - __logf(s);
}

extern "C" void kernel_launch(void* const* d_in, const int* in_sizes, int n_in,
                              void* d_out, int out_size, void* d_ws, size_t ws_size,
                              hipStream_t stream) {
    const float* x   = (const float*)d_in[0];
    const int* src0  = (const int*)d_in[1];
    const int* dst0  = (const int*)d_in[2];
    const int* src1  = (const int*)d_in[3];
    const int* dst1  = (const int*)d_in[4];
    const float* Wl0 = (const float*)d_in[5];
    const float* b0  = (const float*)d_in[6];
    const float* Wr0 = (const float*)d_in[7];
    const float* Wl1 = (const float*)d_in[8];
    const float* b1  = (const float*)d_in[9];
    const float* Wr1 = (const float*)d_in[10];

    char* base = (char*)d_ws;
    size_t off = 0;
    auto alloc = [&](size_t bytes) -> void* {
        off = (off + 255) & ~(size_t)255;
        void* p = base + off;
        off += bytes;
        return p;
    };
    const int N1pad = 120064, N2pad = 12032;  // multiples of BM
    int* c0       = (int*)alloc((size_t)8 * N1c * 4);   // 8 XCD-private copies
    int* c1       = (int*)alloc((size_t)8 * N2c * 4);   // (contiguous with c0)
    int* bs0      = (int*)alloc((size_t)8 * N1c * 4);
    int* bs1      = (int*)alloc((size_t)8 * N2c * 4);
    int* rs0      = (int*)alloc((size_t)(N1c + 1) * 4);
    int* rs1      = (int*)alloc((size_t)(N2c + 1) * 4);
    int* partials = (int*)alloc((size_t)(NB0 + NB1) * 4);
    int* eidx0    = (int*)alloc((size_t)E0c * 4);
    int* eidx1    = (int*)alloc((size_t)E1c * 4);
    u16* A0       = (u16*)alloc((size_t)N1pad * 512 * 2);  // [agg | self] bf16
    u16* hbuf     = (u16*)alloc((size_t)N1pad * 256 * 2);
    u16* A1       = (u16*)alloc((size_t)N2pad * 512 * 2);
    u16* Bt0      = (u16*)alloc((size_t)256 * 512 * 2);
    u16* Bt1      = (u16*)alloc((size_t)128 * 512 * 2);
    float* logits = (float*)alloc((size_t)N2pad * 64 * 4);

    // zero both count arrays (contiguous); scat self-restores them to 0
    hipMemsetAsync(c0, 0, (size_t)8 * (N1c + N2c) * 4, stream);

    const int Etot = E0c + E1c;
    k_hist<<<(Etot + 255) / 256, 256, 0, stream>>>(dst0, dst1, c0, c1);
    k_scanA<<<NB0 + NB1, 256, 0, stream>>>(c0, c1, partials);
    k_scanB<<<1, 256, 0, stream>>>(partials, rs0, rs1);
    k_scanC<<<NB0 + NB1, 256, 0, stream>>>(c0, c1, partials, rs0, rs1, bs0, bs1);
    k_scat<<<(Etot + 255) / 256, 256, 0, stream>>>(src0, dst0, src1, dst1,
                                                   c0, c1, bs0, bs1, eidx0, eidx1);

    k_wcat2<<<(256 * 512 + 128 * 512 + 255) / 256, 256, 0, stream>>>(Bt0, Wl0, Wr0,
                                                                     Bt1, Wl1, Wr1);

    // layer 0
    k_agg0<<<(N1c + 3) / 4, 256, 0, stream>>>(x, eidx0, rs0, A0, N1c);
    dim3 g0(N1pad / BM, 1);
    k_gemm<4, true><<<g0, 512, 0, stream>>>(A0, Bt0, b0, hbuf, N1c, 256, 256);

    // layer 1
    k_agg1<<<(N2c + 3) / 4, 256, 0, stream>>>(hbuf, eidx1, rs1, A1, N2c);
    dim3 g1(N2pad / BM, 1);
    k_gemm<2, false><<<g1, 256, 0, stream>>>(A1, Bt1, b1, logits, N2c, 64, 64);

    k_lsm<<<(N2c + 3) / 4, 256, 0, stream>>>(logits, (float*)d_out, N2c);
}